// Round 7
// baseline (449.881 us; speedup 1.0000x reference)
//
#include <hip/hip_runtime.h>

#define C_CH 173
#define L_IN 400
#define EPSV 1e-5f
#define KFEAT 55360  // C*32*10

typedef __fp16   fp16x2 __attribute__((ext_vector_type(2)));
typedef _Float16 f16x8  __attribute__((ext_vector_type(8)));
typedef float    f32x16 __attribute__((ext_vector_type(16)));

#define Y1T_STRIDE 36   // f16/row = 18 dwords: even (8B-aligned b64), 2-way = free
#define Y1T_ROWS   422  // row r = y1 time (r-3); rows 0..2 and 403..421 zeroed

// 8-lane max via DPP (pure VALU, no DS pipe)
template <int CTRL>
__device__ __forceinline__ float dppf(float v) {
    int s = __builtin_bit_cast(int, v);
    int r = __builtin_amdgcn_update_dpp(0, s, CTRL, 0xF, 0xF, true);
    return __builtin_bit_cast(float, r);
}

// ---------------------------------------------------------------------------
// Tower kernel: one block per (channel c, batch b). 320 threads = 5 waves.
//  phase 1: stage x, w1, w2T(f16,[dt][f][g]), BN consts, zero y1T halos
//  phase 2: conv1(f32) quad-t sliding window (3x b128 per 4 outputs) -> y1T
//  phase 3: conv2 via 7x mfma_32x32x16_f16; BN+ReLU; 8-wide DPP max -> segmax
//  phase 4: pool = max of 5 segments -> feat (f16)
// VGPR discipline: NO sc/sh register arrays in phase 3 (R6's 72-VGPR hoist
// crossed the 64-reg occupancy cliff: 24% -> 14.6%, 226 -> 346 us).
// ---------------------------------------------------------------------------
__global__ __launch_bounds__(320) void tower_kernel(
    const float* __restrict__ x,
    const float* __restrict__ w1, const float* __restrict__ b1,
    const float* __restrict__ g1, const float* __restrict__ beta1,
    const float* __restrict__ m1, const float* __restrict__ v1,
    const float* __restrict__ w2, const float* __restrict__ b2,
    const float* __restrict__ g2, const float* __restrict__ beta2,
    const float* __restrict__ m2, const float* __restrict__ v2,
    _Float16* __restrict__ featH)
{
    __shared__ __align__(16) float    x_s[408];
    __shared__ __align__(16) float    w1_s[144];
    __shared__ __align__(16) _Float16 y1T_s[Y1T_ROWS * Y1T_STRIDE];
    __shared__ __align__(16) _Float16 w2T_s[7 * 512];        // [dt][f][g]
    __shared__ _Float16               segmax_s[32 * 50];     // [f][seg] f16
    __shared__ float scale1_s[16], shift1_s[16], scale2_s[32], shift2_s[32];

    const int c   = blockIdx.x;
    const int b   = blockIdx.y;
    const int tid = threadIdx.x;

    // ---- phase 1: staging ----
    const float* xrow = x + ((size_t)b * C_CH + c) * L_IN;
    for (int i = tid; i < 408; i += 320)
        x_s[i] = (i >= 4 && i < 404) ? xrow[i - 4] : 0.0f;

    for (int i = tid; i < 144; i += 320)
        w1_s[i] = w1[c * 144 + i];

    // w2 via float4 (896 xfers), scatter to w2T[dt][f][g] f16
    for (int idx = tid; idx < 896; idx += 320) {
        float4 v = *(const float4*)(w2 + (size_t)c * 3584 + idx * 4);
        int i0 = idx * 4;
        int f = i0 / 112;
        int r = i0 - f * 112;
        float vv[4] = {v.x, v.y, v.z, v.w};
#pragma unroll
        for (int k = 0; k < 4; ++k) {
            int rr = r + k;                 // 112 % 4 == 0 -> same f
            int g = rr / 7, dt = rr - g * 7;
            w2T_s[dt * 512 + f * 16 + g] = (_Float16)vv[k];
        }
    }

    // zero y1T halo rows 0..2 and 403..421 (22 rows x 18 dwords)
    for (int i = tid; i < 22 * 18; i += 320) {
        int r = i / 18, cidx = i - r * 18;
        int row = (r < 3) ? r : (400 + r);
        ((int*)y1T_s)[row * 18 + cidx] = 0;
    }

    if (tid < 16) {
        int cf = c * 16 + tid;
        float inv = g1[cf] * rsqrtf(v1[cf] + EPSV);
        scale1_s[tid] = inv;
        shift1_s[tid] = (b1[cf] - m1[cf]) * inv + beta1[cf];
    }
    if (tid >= 64 && tid < 96) {
        int f = tid - 64;
        int cf = c * 32 + f;
        float inv = g2[cf] * rsqrtf(v2[cf] + EPSV);
        scale2_s[f] = inv;
        shift2_s[f] = (b2[cf] - m2[cf]) * inv + beta2[cf];
    }
    __syncthreads();

    // ---- phase 2: conv1 + BN + ReLU -> y1T (quad-t, b128 x-reads) ----
    {
        const int g0 = tid & 15;
        float wreg[9];
#pragma unroll
        for (int k = 0; k < 9; ++k) wreg[k] = w1_s[g0 * 9 + k];
        const float s1  = scale1_s[g0];
        const float sh1 = shift1_s[g0];

#pragma unroll
        for (int it = 0; it < 5; ++it) {
            const int idx = tid + it * 320;
            const int t0  = (idx >> 4) * 4;
            float xv[12];
            const float4 a0 = *(const float4*)(x_s + t0);
            const float4 a1 = *(const float4*)(x_s + t0 + 4);
            const float4 a2 = *(const float4*)(x_s + t0 + 8);
            xv[0] = a0.x; xv[1] = a0.y; xv[2]  = a0.z; xv[3]  = a0.w;
            xv[4] = a1.x; xv[5] = a1.y; xv[6]  = a1.z; xv[7]  = a1.w;
            xv[8] = a2.x; xv[9] = a2.y; xv[10] = a2.z; xv[11] = a2.w;
#pragma unroll
            for (int j = 0; j < 4; ++j) {
                float acc = 0.0f;
#pragma unroll
                for (int k = 0; k < 9; ++k) acc += wreg[k] * xv[j + k];
                float val = acc * s1 + sh1;
                val = val > 0.0f ? val : 0.0f;
                y1T_s[(t0 + j + 3) * Y1T_STRIDE + g0] = (_Float16)val;
            }
        }
    }
    __syncthreads();

    // ---- phase 3: conv2 MFMA + BN/ReLU + in-register 8-seg max ----
    {
        const int wv    = tid >> 6;
        const int lane  = tid & 63;
        const int nlane = lane & 31;
        const int half  = lane >> 5;

        union F8q { int4 q; f16x8 h; } af[7];
#pragma unroll
        for (int dt = 0; dt < 7; ++dt)
            af[dt].q = *(const int4*)((const int*)w2T_s + dt * 256 + nlane * 8 + half * 4);

        for (int tile = wv; tile < 13; tile += 5) {
            const int t0 = tile * 32 + nlane;
            f32x16 acc;
#pragma unroll
            for (int i = 0; i < 16; ++i) acc[i] = 0.0f;

#pragma unroll
            for (int dt = 0; dt < 7; ++dt) {
                const int* p = (const int*)y1T_s + (t0 + dt) * 18 + half * 4;
                union { int2 d[2]; f16x8 h; } bf;
                bf.d[0] = *(const int2*)p;
                bf.d[1] = *(const int2*)(p + 2);
                acc = __builtin_amdgcn_mfma_f32_32x32x16_f16(af[dt].h, bf.h, acc, 0, 0, 0);
            }

            const bool wr  = ((nlane & 7) == 0) && (t0 < 400);
            const int  seg = t0 >> 3;       // segment of 8 t-values
#pragma unroll
            for (int reg = 0; reg < 16; ++reg) {
                int f = (reg & 3) + 8 * (reg >> 2) + 4 * half;
                float v = acc[reg] * scale2_s[f] + shift2_s[f];
                v = fmaxf(v, 0.0f);
                v = fmaxf(v, dppf<0xB1>(v));    // xor 1 (quad_perm 1,0,3,2)
                v = fmaxf(v, dppf<0x4E>(v));    // xor 2 (quad_perm 2,3,0,1)
                v = fmaxf(v, dppf<0x141>(v));   // row_half_mirror (combine quads)
                if (wr) segmax_s[f * 50 + seg] = (_Float16)v;
            }
        }
    }
    __syncthreads();

    // ---- phase 4: pool(40) = max of 5 segment-maxes -> feat f16 ----
    {
        const int f = tid & 31;
        const int p = tid >> 5;
        float m = 0.0f;                      // post-ReLU values >= 0
#pragma unroll
        for (int k = 0; k < 5; ++k)
            m = fmaxf(m, (float)segmax_s[f * 50 + p * 5 + k]);
        featH[(size_t)b * KFEAT + (c * 32 + f) * 10 + p] = (_Float16)m;
    }
}

// ---------------------------------------------------------------------------
// FC1 f16 MFMA GEMM, split-K WITHOUT atomics: 173 blocks x KC=320 (20 steps).
// Each block writes a disjoint partial tile part[kb][128][64] (coalesced
// 128B chunks). R2..R6's fc1 tail was ~5.7M device-scope atomicAdds onto
// 8192 addresses -- that serialization was the hidden ~90 us.
// ---------------------------------------------------------------------------
__global__ __launch_bounds__(256) void fc1_kernel(
    const _Float16* __restrict__ featH, const float* __restrict__ wc1,
    float* __restrict__ part)
{
    const int tid   = threadIdx.x;
    const int kb    = blockIdx.x;
    const int k0    = kb * 320;
    const int lane  = tid & 63;
    const int wv    = tid >> 6;
    const int nlane = lane & 31;
    const int half  = lane >> 5;
    const int jrow  = wv * 32 + nlane;

    const float*    ap  = wc1   + (size_t)jrow * KFEAT + k0 + half * 8;
    const _Float16* b0p = featH + (size_t)nlane * KFEAT + k0 + half * 8;
    const _Float16* b1p = featH + (size_t)(nlane + 32) * KFEAT + k0 + half * 8;

    f32x16 acc0, acc1;
#pragma unroll
    for (int i = 0; i < 16; ++i) { acc0[i] = 0.0f; acc1[i] = 0.0f; }

#pragma unroll 2
    for (int s = 0; s < 20; ++s) {
        const float4 aw0 = *(const float4*)(ap + s * 16);
        const float4 aw1 = *(const float4*)(ap + s * 16 + 4);
        union { fp16x2 v2[4]; f16x8 h; } a;
        a.v2[0] = __builtin_amdgcn_cvt_pkrtz(aw0.x, aw0.y);
        a.v2[1] = __builtin_amdgcn_cvt_pkrtz(aw0.z, aw0.w);
        a.v2[2] = __builtin_amdgcn_cvt_pkrtz(aw1.x, aw1.y);
        a.v2[3] = __builtin_amdgcn_cvt_pkrtz(aw1.z, aw1.w);

        union { int4 q; f16x8 h; } b0, b1;
        b0.q = *(const int4*)(b0p + s * 16);
        b1.q = *(const int4*)(b1p + s * 16);

        acc0 = __builtin_amdgcn_mfma_f32_32x32x16_f16(a.h, b0.h, acc0, 0, 0, 0);
        acc1 = __builtin_amdgcn_mfma_f32_32x32x16_f16(a.h, b1.h, acc1, 0, 0, 0);
    }

    float* pt = part + (size_t)kb * 8192;
#pragma unroll
    for (int reg = 0; reg < 16; ++reg) {
        int j = wv * 32 + (reg & 3) + 8 * (reg >> 2) + 4 * half;
        pt[j * 64 + nlane]      = acc0[reg];
        pt[j * 64 + 32 + nlane] = acc1[reg];
    }
}

// ---------------------------------------------------------------------------
// Reduce partials: h[idx] = sum_kb part[kb][idx], idx = j*64+b. Coalesced.
// ---------------------------------------------------------------------------
__global__ __launch_bounds__(256) void reduce_kernel(
    const float* __restrict__ part, float* __restrict__ h_ws)
{
    const int idx = blockIdx.x * 256 + threadIdx.x;   // 0..8191
    float s = 0.0f;
    for (int kb = 0; kb < 173; ++kb)
        s += part[(size_t)kb * 8192 + idx];
    h_ws[idx] = s;
}

// ---------------------------------------------------------------------------
// FC2: out[b] = bc2 + sum_j wc2[j] * relu(h[j][b] + bc1[j])
// ---------------------------------------------------------------------------
__global__ __launch_bounds__(64) void fc2_kernel(
    const float* __restrict__ h_ws, const float* __restrict__ bc1,
    const float* __restrict__ wc2, const float* __restrict__ bc2,
    float* __restrict__ out)
{
    const int b = threadIdx.x;
    float acc = bc2[0];
    for (int j = 0; j < 128; ++j) {
        float hv = h_ws[j * 64 + b] + bc1[j];
        hv = hv > 0.0f ? hv : 0.0f;
        acc += wc2[j] * hv;
    }
    out[b] = acc;
}

extern "C" void kernel_launch(void* const* d_in, const int* in_sizes, int n_in,
                              void* d_out, int out_size, void* d_ws, size_t ws_size,
                              hipStream_t stream)
{
    const float* x     = (const float*)d_in[0];
    const float* w1    = (const float*)d_in[1];
    const float* b1    = (const float*)d_in[2];
    const float* g1    = (const float*)d_in[3];
    const float* beta1 = (const float*)d_in[4];
    const float* m1    = (const float*)d_in[5];
    const float* v1    = (const float*)d_in[6];
    const float* w2    = (const float*)d_in[7];
    const float* b2    = (const float*)d_in[8];
    const float* g2    = (const float*)d_in[9];
    const float* beta2 = (const float*)d_in[10];
    const float* m2    = (const float*)d_in[11];
    const float* v2    = (const float*)d_in[12];
    const float* wc1   = (const float*)d_in[13];
    const float* bc1   = (const float*)d_in[14];
    const float* wc2   = (const float*)d_in[15];
    const float* bc2   = (const float*)d_in[16];

    _Float16* featH = (_Float16*)d_ws;                          // 7.09 MB
    float*    part  = (float*)((char*)d_ws + (size_t)64 * KFEAT * 2);       // 173*8192*4 = 5.67 MB
    float*    h_ws  = (float*)((char*)part + (size_t)173 * 8192 * 4);       // 32 KB

    dim3 gtower(C_CH, 64);
    hipLaunchKernelGGL(tower_kernel, gtower, dim3(320), 0, stream,
                       x, w1, b1, g1, beta1, m1, v1,
                       w2, b2, g2, beta2, m2, v2, featH);

    hipLaunchKernelGGL(fc1_kernel, dim3(173), dim3(256), 0, stream,
                       featH, wc1, part);

    hipLaunchKernelGGL(reduce_kernel, dim3(32), dim3(256), 0, stream,
                       part, h_ws);

    hipLaunchKernelGGL(fc2_kernel, dim3(1), dim3(64), 0, stream,
                       h_ws, bc1, wc2, bc2, (float*)d_out);
}

// Round 8
// 347.626 us; speedup vs baseline: 1.2942x; 1.2942x over previous
//
#include <hip/hip_runtime.h>

#define C_CH 173
#define L_IN 400
#define EPSV 1e-5f
#define KFEAT 55360  // C*32*10

typedef __fp16   fp16x2 __attribute__((ext_vector_type(2)));
typedef _Float16 f16x8  __attribute__((ext_vector_type(8)));
typedef float    f32x16 __attribute__((ext_vector_type(16)));

#define Y1T_STRIDE 36   // f16/row = 18 dwords: even (8B-aligned b64), 2-way = free
#define Y1T_ROWS   422  // row r = y1 time (r-3); rows 0..2 and 403..421 zeroed

// 8-lane max via DPP (pure VALU, no DS pipe)
template <int CTRL>
__device__ __forceinline__ float dppf(float v) {
    int s = __builtin_bit_cast(int, v);
    int r = __builtin_amdgcn_update_dpp(0, s, CTRL, 0xF, 0xF, true);
    return __builtin_bit_cast(float, r);
}

// ---------------------------------------------------------------------------
// Tower kernel: one block per (channel c, batch b). 320 threads = 5 waves.
//  phase 1: stage x, w1, w2T(f16,[dt][f][g]), BN consts, zero y1T halos
//  phase 2: conv1(f32) scalar form -- R4's proven 52-VGPR version. The R5
//           quad-t rewrite (b128 x-reads, xv[12]/wreg[9] hoists over a 5x
//           unroll) compiled to 72 VGPR, crossing the 64-reg cliff:
//           waves/SIMD 8->4, blocks/CU 3->2, tower 226 -> 346 us (R6/R7).
//  phase 3: conv2 via 7x mfma_32x32x16_f16; BN+ReLU; 8-wide DPP max -> segmax
//  phase 4: pool = max of 5 segments -> feat (f16)
// ---------------------------------------------------------------------------
__global__ __launch_bounds__(320) void tower_kernel(
    const float* __restrict__ x,
    const float* __restrict__ w1, const float* __restrict__ b1,
    const float* __restrict__ g1, const float* __restrict__ beta1,
    const float* __restrict__ m1, const float* __restrict__ v1,
    const float* __restrict__ w2, const float* __restrict__ b2,
    const float* __restrict__ g2, const float* __restrict__ beta2,
    const float* __restrict__ m2, const float* __restrict__ v2,
    _Float16* __restrict__ featH)
{
    __shared__ __align__(16) float    x_s[408];
    __shared__ __align__(16) float    w1_s[144];
    __shared__ __align__(16) _Float16 y1T_s[Y1T_ROWS * Y1T_STRIDE];
    __shared__ __align__(16) _Float16 w2T_s[7 * 512];        // [dt][f][g]
    __shared__ _Float16               segmax_s[32 * 50];     // [f][seg] f16
    __shared__ float scale1_s[16], shift1_s[16], scale2_s[32], shift2_s[32];

    const int c   = blockIdx.x;
    const int b   = blockIdx.y;
    const int tid = threadIdx.x;

    // ---- phase 1: staging ----
    const float* xrow = x + ((size_t)b * C_CH + c) * L_IN;
    for (int i = tid; i < 408; i += 320)
        x_s[i] = (i >= 4 && i < 404) ? xrow[i - 4] : 0.0f;

    for (int i = tid; i < 144; i += 320)
        w1_s[i] = w1[c * 144 + i];

    // w2 via float4 (896 xfers), scatter to w2T[dt][f][g] f16
    for (int idx = tid; idx < 896; idx += 320) {
        float4 v = *(const float4*)(w2 + (size_t)c * 3584 + idx * 4);
        int i0 = idx * 4;
        int f = i0 / 112;
        int r = i0 - f * 112;
        float vv[4] = {v.x, v.y, v.z, v.w};
#pragma unroll
        for (int k = 0; k < 4; ++k) {
            int rr = r + k;                 // 112 % 4 == 0 -> same f
            int g = rr / 7, dt = rr - g * 7;
            w2T_s[dt * 512 + f * 16 + g] = (_Float16)vv[k];
        }
    }

    // zero y1T halo rows 0..2 and 403..421 (22 rows x 18 dwords)
    for (int i = tid; i < 22 * 18; i += 320) {
        int r = i / 18, cidx = i - r * 18;
        int row = (r < 3) ? r : (400 + r);
        ((int*)y1T_s)[row * 18 + cidx] = 0;
    }

    if (tid < 16) {
        int cf = c * 16 + tid;
        float inv = g1[cf] * rsqrtf(v1[cf] + EPSV);
        scale1_s[tid] = inv;
        shift1_s[tid] = (b1[cf] - m1[cf]) * inv + beta1[cf];
    }
    if (tid >= 64 && tid < 96) {
        int f = tid - 64;
        int cf = c * 32 + f;
        float inv = g2[cf] * rsqrtf(v2[cf] + EPSV);
        scale2_s[f] = inv;
        shift2_s[f] = (b2[cf] - m2[cf]) * inv + beta2[cf];
    }
    __syncthreads();

    // ---- phase 2: conv1 + BN + ReLU -> y1T (R4 scalar form, 52 VGPR) ----
    for (int i = tid; i < 6400; i += 320) {
        int g = i & 15;
        int t = i >> 4;
        const float* wp = &w1_s[g * 9];
        float acc = 0.0f;
#pragma unroll
        for (int k = 0; k < 9; ++k) acc += wp[k] * x_s[t + k];
        float val = acc * scale1_s[g] + shift1_s[g];
        val = val > 0.0f ? val : 0.0f;
        y1T_s[(t + 3) * Y1T_STRIDE + g] = (_Float16)val;
    }
    __syncthreads();

    // ---- phase 3: conv2 MFMA + BN/ReLU + in-register 8-seg max ----
    {
        const int wv    = tid >> 6;
        const int lane  = tid & 63;
        const int nlane = lane & 31;
        const int half  = lane >> 5;

        union F8q { int4 q; f16x8 h; } af[7];
#pragma unroll
        for (int dt = 0; dt < 7; ++dt)
            af[dt].q = *(const int4*)((const int*)w2T_s + dt * 256 + nlane * 8 + half * 4);

        for (int tile = wv; tile < 13; tile += 5) {
            const int t0 = tile * 32 + nlane;
            f32x16 acc;
#pragma unroll
            for (int i = 0; i < 16; ++i) acc[i] = 0.0f;

#pragma unroll
            for (int dt = 0; dt < 7; ++dt) {
                const int* p = (const int*)y1T_s + (t0 + dt) * 18 + half * 4;
                union { int2 d[2]; f16x8 h; } bf;
                bf.d[0] = *(const int2*)p;
                bf.d[1] = *(const int2*)(p + 2);
                acc = __builtin_amdgcn_mfma_f32_32x32x16_f16(af[dt].h, bf.h, acc, 0, 0, 0);
            }

            const bool wr  = ((nlane & 7) == 0) && (t0 < 400);
            const int  seg = t0 >> 3;       // segment of 8 t-values
#pragma unroll
            for (int reg = 0; reg < 16; ++reg) {
                int f = (reg & 3) + 8 * (reg >> 2) + 4 * half;
                float v = acc[reg] * scale2_s[f] + shift2_s[f];
                v = fmaxf(v, 0.0f);
                v = fmaxf(v, dppf<0xB1>(v));    // xor 1 (quad_perm 1,0,3,2)
                v = fmaxf(v, dppf<0x4E>(v));    // xor 2 (quad_perm 2,3,0,1)
                v = fmaxf(v, dppf<0x141>(v));   // row_half_mirror (combine quads)
                if (wr) segmax_s[f * 50 + seg] = (_Float16)v;
            }
        }
    }
    __syncthreads();

    // ---- phase 4: pool(40) = max of 5 segment-maxes -> feat f16 ----
    {
        const int f = tid & 31;
        const int p = tid >> 5;
        float m = 0.0f;                      // post-ReLU values >= 0
#pragma unroll
        for (int k = 0; k < 5; ++k)
            m = fmaxf(m, (float)segmax_s[f * 50 + p * 5 + k]);
        featH[(size_t)b * KFEAT + (c * 32 + f) * 10 + p] = (_Float16)m;
    }
}

// ---------------------------------------------------------------------------
// FC1 f16 MFMA GEMM, split-K without atomics: 173 blocks x KC=320 (20 steps).
// Each block writes a disjoint partial tile part[kb][128][64].
// ---------------------------------------------------------------------------
__global__ __launch_bounds__(256) void fc1_kernel(
    const _Float16* __restrict__ featH, const float* __restrict__ wc1,
    float* __restrict__ part)
{
    const int tid   = threadIdx.x;
    const int kb    = blockIdx.x;
    const int k0    = kb * 320;
    const int lane  = tid & 63;
    const int wv    = tid >> 6;
    const int nlane = lane & 31;
    const int half  = lane >> 5;
    const int jrow  = wv * 32 + nlane;

    const float*    ap  = wc1   + (size_t)jrow * KFEAT + k0 + half * 8;
    const _Float16* b0p = featH + (size_t)nlane * KFEAT + k0 + half * 8;
    const _Float16* b1p = featH + (size_t)(nlane + 32) * KFEAT + k0 + half * 8;

    f32x16 acc0, acc1;
#pragma unroll
    for (int i = 0; i < 16; ++i) { acc0[i] = 0.0f; acc1[i] = 0.0f; }

#pragma unroll 2
    for (int s = 0; s < 20; ++s) {
        const float4 aw0 = *(const float4*)(ap + s * 16);
        const float4 aw1 = *(const float4*)(ap + s * 16 + 4);
        union { fp16x2 v2[4]; f16x8 h; } a;
        a.v2[0] = __builtin_amdgcn_cvt_pkrtz(aw0.x, aw0.y);
        a.v2[1] = __builtin_amdgcn_cvt_pkrtz(aw0.z, aw0.w);
        a.v2[2] = __builtin_amdgcn_cvt_pkrtz(aw1.x, aw1.y);
        a.v2[3] = __builtin_amdgcn_cvt_pkrtz(aw1.z, aw1.w);

        union { int4 q; f16x8 h; } b0, b1;
        b0.q = *(const int4*)(b0p + s * 16);
        b1.q = *(const int4*)(b1p + s * 16);

        acc0 = __builtin_amdgcn_mfma_f32_32x32x16_f16(a.h, b0.h, acc0, 0, 0, 0);
        acc1 = __builtin_amdgcn_mfma_f32_32x32x16_f16(a.h, b1.h, acc1, 0, 0, 0);
    }

    float* pt = part + (size_t)kb * 8192;
#pragma unroll
    for (int reg = 0; reg < 16; ++reg) {
        int j = wv * 32 + (reg & 3) + 8 * (reg >> 2) + 4 * half;
        pt[j * 64 + nlane]      = acc0[reg];
        pt[j * 64 + 32 + nlane] = acc1[reg];
    }
}

// ---------------------------------------------------------------------------
// Reduce partials: h[idx] = sum_kb part[kb][idx], idx = j*64+b. Coalesced.
// ---------------------------------------------------------------------------
__global__ __launch_bounds__(256) void reduce_kernel(
    const float* __restrict__ part, float* __restrict__ h_ws)
{
    const int idx = blockIdx.x * 256 + threadIdx.x;   // 0..8191
    float s = 0.0f;
    for (int kb = 0; kb < 173; ++kb)
        s += part[(size_t)kb * 8192 + idx];
    h_ws[idx] = s;
}

// ---------------------------------------------------------------------------
// FC2: out[b] = bc2 + sum_j wc2[j] * relu(h[j][b] + bc1[j])
// ---------------------------------------------------------------------------
__global__ __launch_bounds__(64) void fc2_kernel(
    const float* __restrict__ h_ws, const float* __restrict__ bc1,
    const float* __restrict__ wc2, const float* __restrict__ bc2,
    float* __restrict__ out)
{
    const int b = threadIdx.x;
    float acc = bc2[0];
    for (int j = 0; j < 128; ++j) {
        float hv = h_ws[j * 64 + b] + bc1[j];
        hv = hv > 0.0f ? hv : 0.0f;
        acc += wc2[j] * hv;
    }
    out[b] = acc;
}

extern "C" void kernel_launch(void* const* d_in, const int* in_sizes, int n_in,
                              void* d_out, int out_size, void* d_ws, size_t ws_size,
                              hipStream_t stream)
{
    const float* x     = (const float*)d_in[0];
    const float* w1    = (const float*)d_in[1];
    const float* b1    = (const float*)d_in[2];
    const float* g1    = (const float*)d_in[3];
    const float* beta1 = (const float*)d_in[4];
    const float* m1    = (const float*)d_in[5];
    const float* v1    = (const float*)d_in[6];
    const float* w2    = (const float*)d_in[7];
    const float* b2    = (const float*)d_in[8];
    const float* g2    = (const float*)d_in[9];
    const float* beta2 = (const float*)d_in[10];
    const float* m2    = (const float*)d_in[11];
    const float* v2    = (const float*)d_in[12];
    const float* wc1   = (const float*)d_in[13];
    const float* bc1   = (const float*)d_in[14];
    const float* wc2   = (const float*)d_in[15];
    const float* bc2   = (const float*)d_in[16];

    _Float16* featH = (_Float16*)d_ws;                                      // 7.09 MB
    float*    part  = (float*)((char*)d_ws + (size_t)64 * KFEAT * 2);       // 173*8192*4 = 5.67 MB
    float*    h_ws  = (float*)((char*)part + (size_t)173 * 8192 * 4);       // 32 KB

    dim3 gtower(C_CH, 64);
    hipLaunchKernelGGL(tower_kernel, gtower, dim3(320), 0, stream,
                       x, w1, b1, g1, beta1, m1, v1,
                       w2, b2, g2, beta2, m2, v2, featH);

    hipLaunchKernelGGL(fc1_kernel, dim3(173), dim3(256), 0, stream,
                       featH, wc1, part);

    hipLaunchKernelGGL(reduce_kernel, dim3(32), dim3(256), 0, stream,
                       part, h_ws);

    hipLaunchKernelGGL(fc2_kernel, dim3(1), dim3(64), 0, stream,
                       h_ws, bc1, wc2, bc2, (float*)d_out);
}

// Round 9
// 307.699 us; speedup vs baseline: 1.4621x; 1.1298x over previous
//
#include <hip/hip_runtime.h>

#define C_CH 173
#define L_IN 400
#define EPSV 1e-5f
#define KFEAT 55360  // C*32*10

typedef __fp16   fp16x2 __attribute__((ext_vector_type(2)));
typedef _Float16 f16x8  __attribute__((ext_vector_type(8)));
typedef float    f32x4  __attribute__((ext_vector_type(4)));
typedef float    f32x16 __attribute__((ext_vector_type(16)));

#define Y1T_STRIDE 36   // f16/row = 18 dwords: even (8B-aligned b64), 2-way = free
#define Y1T_ROWS   406  // row r = y1 time t+3; rows 0..2, 403..405 zeroed halo

// 8-lane max via DPP (pure VALU, no DS pipe)
template <int CTRL>
__device__ __forceinline__ float dppf(float v) {
    int s = __builtin_bit_cast(int, v);
    int r = __builtin_amdgcn_update_dpp(0, s, CTRL, 0xF, 0xF, true);
    return __builtin_bit_cast(float, r);
}

// ---------------------------------------------------------------------------
// Tower kernel: one block per (channel c, batch b). 320 threads = 5 waves.
//  phase 1: stage x (f16, TWO parity copies xa/xb), w1T (f16 16x32, K-padded),
//           w2T (f16 [dt][f][g]), BN consts, zero y1T halo rows
//  phase 2: conv1 via mfma_16x16x32_f16 (K=9 padded to 32): per wave 5 tiles,
//           B-frag = 4x ds_read_b32 from parity-selected x copy (lane's
//           8-f16 window is always dword-aligned in its copy), epilogue
//           BN+ReLU -> one ds_write_b64 (4 consecutive g at fixed t).
//           Replaces R8's scalar conv1: 211 -> ~34 DS instrs/wave; the DS
//           pipe was ~6100 cyc/block of R8's ~240us tower.
//  phase 3: conv2 via 7x mfma_32x32x16_f16; BN+ReLU; 8-wide DPP max -> segmax
//  phase 4: pool = max of 5 segments -> feat (f16)
// LDS 42736 B -> <= 43520: 3 blocks/CU. VGPR pinned <=64 via
// __launch_bounds__(320,8) (R6 showed crossing 64 costs 1.5x).
// ---------------------------------------------------------------------------
__global__ __launch_bounds__(320, 8) void tower_kernel(
    const float* __restrict__ x,
    const float* __restrict__ w1, const float* __restrict__ b1,
    const float* __restrict__ g1, const float* __restrict__ beta1,
    const float* __restrict__ m1, const float* __restrict__ v1,
    const float* __restrict__ w2, const float* __restrict__ b2,
    const float* __restrict__ g2, const float* __restrict__ beta2,
    const float* __restrict__ m2, const float* __restrict__ v2,
    _Float16* __restrict__ featH)
{
    __shared__ __align__(16) _Float16 xa_s[432];             // xa[i] = x_s[i]
    __shared__ __align__(16) _Float16 xb_s[432];             // xb[i] = x_s[i+1]
    __shared__ __align__(16) _Float16 w1T_s[16 * 32];        // [g][k], k>=9 zero
    __shared__ __align__(16) _Float16 y1T_s[Y1T_ROWS * Y1T_STRIDE];
    __shared__ __align__(16) _Float16 w2T_s[7 * 512];        // [dt][f][g]
    __shared__ _Float16               segmax_s[32 * 50];     // [f][seg] f16
    __shared__ float scale1_s[16], shift1_s[16], scale2_s[32], shift2_s[32];

    const int c   = blockIdx.x;
    const int b   = blockIdx.y;
    const int tid = threadIdx.x;

    // ---- phase 1: staging ----
    // x_s[i] = x[i-4] zero-padded; stored f16 in two parity copies.
    const float* xrow = x + ((size_t)b * C_CH + c) * L_IN;
    for (int i = tid; i < 432; i += 320) {
        float v = (i >= 4 && i < 404) ? xrow[i - 4] : 0.0f;
        _Float16 h = (_Float16)v;
        xa_s[i] = h;
        if (i > 0) xb_s[i - 1] = h;
    }
    if (tid == 0) xb_s[431] = (_Float16)0.0f;

    // w1T[g][k] f16, zero-padded K 9->32 (zeros kill B-garbage in MFMA)
    for (int i = tid; i < 512; i += 320) {
        int g = i >> 5, k = i & 31;
        float v = (k < 9) ? w1[c * 144 + g * 9 + k] : 0.0f;
        w1T_s[i] = (_Float16)v;
    }

    // w2 via float4 (896 xfers), scatter to w2T[dt][f][g] f16
    for (int idx = tid; idx < 896; idx += 320) {
        float4 v = *(const float4*)(w2 + (size_t)c * 3584 + idx * 4);
        int i0 = idx * 4;
        int f = i0 / 112;
        int r = i0 - f * 112;
        float vv[4] = {v.x, v.y, v.z, v.w};
#pragma unroll
        for (int k = 0; k < 4; ++k) {
            int rr = r + k;                 // 112 % 4 == 0 -> same f
            int g = rr / 7, dt = rr - g * 7;
            w2T_s[dt * 512 + f * 16 + g] = (_Float16)vv[k];
        }
    }

    // zero y1T halo rows 0..2 and 403..405 (6 rows x 18 dwords)
    for (int i = tid; i < 6 * 18; i += 320) {
        int r = i / 18, cx = i - r * 18;
        int row = (r < 3) ? r : (400 + r);
        ((int*)y1T_s)[row * 18 + cx] = 0;
    }

    if (tid < 16) {
        int cf = c * 16 + tid;
        float inv = g1[cf] * rsqrtf(v1[cf] + EPSV);
        scale1_s[tid] = inv;
        shift1_s[tid] = (b1[cf] - m1[cf]) * inv + beta1[cf];
    }
    if (tid >= 64 && tid < 96) {
        int f = tid - 64;
        int cf = c * 32 + f;
        float inv = g2[cf] * rsqrtf(v2[cf] + EPSV);
        scale2_s[f] = inv;
        shift2_s[f] = (b2[cf] - m2[cf]) * inv + beta2[cf];
    }
    __syncthreads();

    // ---- phase 2: conv1 via mfma_16x16x32_f16 -> y1T ----
    // A[m=g][k] = w1T; B[k][n=t] = x_s[t0+n + k - 4] (x_s shift already +4).
    // Lane: n = nl = lane&15, k-group q = lane>>4 (k = 8q+j).
    // B window f16 index base = t0+nl+8q; parity == nl&1 -> copy select,
    // dword index = base>>1 in the selected copy for BOTH parities.
    {
        const int lane = tid & 63;
        const int wv5  = tid >> 6;         // 0..4
        const int nl   = lane & 15;
        const int q    = lane >> 4;        // 0..3
        union { int4 v; f16x8 h; } a1;
        a1.v = *(const int4*)((const int*)w1T_s + nl * 16 + q * 4);
        float s1r[4], sh1r[4];
#pragma unroll
        for (int r = 0; r < 4; ++r) {      // lane's 4 output g = 4q+r
            s1r[r]  = scale1_s[q * 4 + r];
            sh1r[r] = shift1_s[q * 4 + r];
        }
        const int* xsel = (const int*)((nl & 1) ? xb_s : xa_s);
        for (int tile = 0; tile < 5; ++tile) {
            const int t0 = (wv5 * 5 + tile) * 16;
            const int dw = (t0 + nl + q * 8) >> 1;
            union { int4 v; f16x8 h; } bf;
            bf.v.x = xsel[dw];
            bf.v.y = xsel[dw + 1];
            bf.v.z = xsel[dw + 2];
            bf.v.w = xsel[dw + 3];
            f32x4 acc = {0.0f, 0.0f, 0.0f, 0.0f};
            acc = __builtin_amdgcn_mfma_f32_16x16x32_f16(a1.h, bf.h, acc, 0, 0, 0);
            // D: lane holds t = t0+nl (col), g = 4q+r (row). BN+ReLU, pack,
            // one b64 write: byte addr (t+3)*72 + 8q -> 8B aligned.
            union { _Float16 h[4]; int2 d; } pk;
#pragma unroll
            for (int r = 0; r < 4; ++r) {
                float v = acc[r] * s1r[r] + sh1r[r];
                pk.h[r] = (_Float16)(v > 0.0f ? v : 0.0f);
            }
            *(int2*)((int*)y1T_s + (t0 + nl + 3) * 18 + q * 2) = pk.d;
        }
    }
    __syncthreads();

    // ---- phase 3: conv2 MFMA + BN/ReLU + in-register 8-seg max ----
    {
        const int wv    = tid >> 6;
        const int lane  = tid & 63;
        const int nlane = lane & 31;
        const int half  = lane >> 5;

        union F8q { int4 q; f16x8 h; } af[7];
#pragma unroll
        for (int dt = 0; dt < 7; ++dt)
            af[dt].q = *(const int4*)((const int*)w2T_s + dt * 256 + nlane * 8 + half * 4);

        for (int tile = wv; tile < 13; tile += 5) {
            const int t0  = tile * 32 + nlane;
            const int t0r = t0 < 400 ? t0 : 399;   // clamp: rows > 405 don't exist
            f32x16 acc;
#pragma unroll
            for (int i = 0; i < 16; ++i) acc[i] = 0.0f;

#pragma unroll
            for (int dt = 0; dt < 7; ++dt) {
                const int* p = (const int*)y1T_s + (t0r + dt) * 18 + half * 4;
                union { int2 d[2]; f16x8 h; } bf;
                bf.d[0] = *(const int2*)p;
                bf.d[1] = *(const int2*)(p + 2);
                acc = __builtin_amdgcn_mfma_f32_32x32x16_f16(af[dt].h, bf.h, acc, 0, 0, 0);
            }

            const bool wr  = ((nlane & 7) == 0) && (t0 < 400);
            const int  seg = t0 >> 3;       // segment of 8 t-values
#pragma unroll
            for (int reg = 0; reg < 16; ++reg) {
                int f = (reg & 3) + 8 * (reg >> 2) + 4 * half;
                float v = acc[reg] * scale2_s[f] + shift2_s[f];
                v = fmaxf(v, 0.0f);
                v = fmaxf(v, dppf<0xB1>(v));    // xor 1 (quad_perm 1,0,3,2)
                v = fmaxf(v, dppf<0x4E>(v));    // xor 2 (quad_perm 2,3,0,1)
                v = fmaxf(v, dppf<0x141>(v));   // row_half_mirror (combine quads)
                if (wr) segmax_s[f * 50 + seg] = (_Float16)v;
            }
        }
    }
    __syncthreads();

    // ---- phase 4: pool(40) = max of 5 segment-maxes -> feat f16 ----
    {
        const int f = tid & 31;
        const int p = tid >> 5;
        float m = 0.0f;                      // post-ReLU values >= 0
#pragma unroll
        for (int k = 0; k < 5; ++k)
            m = fmaxf(m, (float)segmax_s[f * 50 + p * 5 + k]);
        featH[(size_t)b * KFEAT + (c * 32 + f) * 10 + p] = (_Float16)m;
    }
}

// ---------------------------------------------------------------------------
// FC1 f16 MFMA GEMM, split-K without atomics: 173 blocks x KC=320 (20 steps).
// Each block writes a disjoint partial tile part[kb][128][64].
// ---------------------------------------------------------------------------
__global__ __launch_bounds__(256) void fc1_kernel(
    const _Float16* __restrict__ featH, const float* __restrict__ wc1,
    float* __restrict__ part)
{
    const int tid   = threadIdx.x;
    const int kb    = blockIdx.x;
    const int k0    = kb * 320;
    const int lane  = tid & 63;
    const int wv    = tid >> 6;
    const int nlane = lane & 31;
    const int half  = lane >> 5;
    const int jrow  = wv * 32 + nlane;

    const float*    ap  = wc1   + (size_t)jrow * KFEAT + k0 + half * 8;
    const _Float16* b0p = featH + (size_t)nlane * KFEAT + k0 + half * 8;
    const _Float16* b1p = featH + (size_t)(nlane + 32) * KFEAT + k0 + half * 8;

    f32x16 acc0, acc1;
#pragma unroll
    for (int i = 0; i < 16; ++i) { acc0[i] = 0.0f; acc1[i] = 0.0f; }

#pragma unroll 2
    for (int s = 0; s < 20; ++s) {
        const float4 aw0 = *(const float4*)(ap + s * 16);
        const float4 aw1 = *(const float4*)(ap + s * 16 + 4);
        union { fp16x2 v2[4]; f16x8 h; } a;
        a.v2[0] = __builtin_amdgcn_cvt_pkrtz(aw0.x, aw0.y);
        a.v2[1] = __builtin_amdgcn_cvt_pkrtz(aw0.z, aw0.w);
        a.v2[2] = __builtin_amdgcn_cvt_pkrtz(aw1.x, aw1.y);
        a.v2[3] = __builtin_amdgcn_cvt_pkrtz(aw1.z, aw1.w);

        union { int4 q; f16x8 h; } b0, b1;
        b0.q = *(const int4*)(b0p + s * 16);
        b1.q = *(const int4*)(b1p + s * 16);

        acc0 = __builtin_amdgcn_mfma_f32_32x32x16_f16(a.h, b0.h, acc0, 0, 0, 0);
        acc1 = __builtin_amdgcn_mfma_f32_32x32x16_f16(a.h, b1.h, acc1, 0, 0, 0);
    }

    float* pt = part + (size_t)kb * 8192;
#pragma unroll
    for (int reg = 0; reg < 16; ++reg) {
        int j = wv * 32 + (reg & 3) + 8 * (reg >> 2) + 4 * half;
        pt[j * 64 + nlane]      = acc0[reg];
        pt[j * 64 + 32 + nlane] = acc1[reg];
    }
}

// ---------------------------------------------------------------------------
// Reduce partials: h[idx] = sum_kb part[kb][idx], idx = j*64+b. Coalesced.
// ---------------------------------------------------------------------------
__global__ __launch_bounds__(256) void reduce_kernel(
    const float* __restrict__ part, float* __restrict__ h_ws)
{
    const int idx = blockIdx.x * 256 + threadIdx.x;   // 0..8191
    float s = 0.0f;
    for (int kb = 0; kb < 173; ++kb)
        s += part[(size_t)kb * 8192 + idx];
    h_ws[idx] = s;
}

// ---------------------------------------------------------------------------
// FC2: out[b] = bc2 + sum_j wc2[j] * relu(h[j][b] + bc1[j])
// ---------------------------------------------------------------------------
__global__ __launch_bounds__(64) void fc2_kernel(
    const float* __restrict__ h_ws, const float* __restrict__ bc1,
    const float* __restrict__ wc2, const float* __restrict__ bc2,
    float* __restrict__ out)
{
    const int b = threadIdx.x;
    float acc = bc2[0];
    for (int j = 0; j < 128; ++j) {
        float hv = h_ws[j * 64 + b] + bc1[j];
        hv = hv > 0.0f ? hv : 0.0f;
        acc += wc2[j] * hv;
    }
    out[b] = acc;
}

extern "C" void kernel_launch(void* const* d_in, const int* in_sizes, int n_in,
                              void* d_out, int out_size, void* d_ws, size_t ws_size,
                              hipStream_t stream)
{
    const float* x     = (const float*)d_in[0];
    const float* w1    = (const float*)d_in[1];
    const float* b1    = (const float*)d_in[2];
    const float* g1    = (const float*)d_in[3];
    const float* beta1 = (const float*)d_in[4];
    const float* m1    = (const float*)d_in[5];
    const float* v1    = (const float*)d_in[6];
    const float* w2    = (const float*)d_in[7];
    const float* b2    = (const float*)d_in[8];
    const float* g2    = (const float*)d_in[9];
    const float* beta2 = (const float*)d_in[10];
    const float* m2    = (const float*)d_in[11];
    const float* v2    = (const float*)d_in[12];
    const float* wc1   = (const float*)d_in[13];
    const float* bc1   = (const float*)d_in[14];
    const float* wc2   = (const float*)d_in[15];
    const float* bc2   = (const float*)d_in[16];

    _Float16* featH = (_Float16*)d_ws;                                      // 7.09 MB
    float*    part  = (float*)((char*)d_ws + (size_t)64 * KFEAT * 2);       // 173*8192*4 = 5.67 MB
    float*    h_ws  = (float*)((char*)part + (size_t)173 * 8192 * 4);       // 32 KB

    dim3 gtower(C_CH, 64);
    hipLaunchKernelGGL(tower_kernel, gtower, dim3(320), 0, stream,
                       x, w1, b1, g1, beta1, m1, v1,
                       w2, b2, g2, beta2, m2, v2, featH);

    hipLaunchKernelGGL(fc1_kernel, dim3(173), dim3(256), 0, stream,
                       featH, wc1, part);

    hipLaunchKernelGGL(reduce_kernel, dim3(32), dim3(256), 0, stream,
                       part, h_ws);

    hipLaunchKernelGGL(fc2_kernel, dim3(1), dim3(64), 0, stream,
                       h_ws, bc1, wc2, bc2, (float*)d_out);
}

// Round 10
// 285.406 us; speedup vs baseline: 1.5763x; 1.0781x over previous
//
#include <hip/hip_runtime.h>

#define C_CH 173
#define L_IN 400
#define EPSV 1e-5f
#define KFEAT 55360  // C*32*10

typedef __fp16   fp16x2 __attribute__((ext_vector_type(2)));
typedef _Float16 f16x8  __attribute__((ext_vector_type(8)));
typedef float    f32x4  __attribute__((ext_vector_type(4)));
typedef float    f32x16 __attribute__((ext_vector_type(16)));

#define Y1T_STRIDE 36   // f16/row = 18 dwords: even (8B-aligned b64), 2-way = free
#define Y1T_ROWS   406  // row r = y1 time t+3; rows 0..2, 403..405 zeroed halo

#define N1 (173 * 3584)  // w2T elems
#define N2 (173 * 512)   // w1T elems
#define N3 (173 * 96)    // BN consts per c: s1[16] sh1[16] s2[32] sh2[32]

// 8-lane max via DPP (pure VALU, no DS pipe)
template <int CTRL>
__device__ __forceinline__ float dppf(float v) {
    int s = __builtin_bit_cast(int, v);
    int r = __builtin_amdgcn_update_dpp(0, s, CTRL, 0xF, 0xF, true);
    return __builtin_bit_cast(float, r);
}

// ---------------------------------------------------------------------------
// Prep kernel: materialize per-channel weight layouts + BN consts ONCE per
// call (R9 recomputed them in every (c,b) tower block = 64x redundant, with
// constant-divisions and scattered ds_write_b16 each time).
//  w2T_g[c][dt*512 + f*16 + g] f16 ; w1T_g[c][g*32+k] f16 (k>=9 zero)
//  sc_g[c*96 + r]: r<16 scale1 | r<32 shift1 | r<64 scale2 | r<96 shift2
// ---------------------------------------------------------------------------
__global__ __launch_bounds__(256) void prep_kernel(
    const float* __restrict__ w1, const float* __restrict__ b1,
    const float* __restrict__ g1, const float* __restrict__ beta1,
    const float* __restrict__ m1, const float* __restrict__ v1,
    const float* __restrict__ w2, const float* __restrict__ b2,
    const float* __restrict__ g2, const float* __restrict__ beta2,
    const float* __restrict__ m2, const float* __restrict__ v2,
    _Float16* __restrict__ w2T_g, _Float16* __restrict__ w1T_g,
    float* __restrict__ sc_g)
{
    const int idx = blockIdx.x * 256 + threadIdx.x;
    if (idx < N1) {
        int c = idx / 3584, r = idx - c * 3584;
        int dt = r >> 9, fg = r & 511;
        int f = fg >> 4, g = fg & 15;
        w2T_g[idx] = (_Float16)w2[c * 3584 + f * 112 + g * 7 + dt];
    } else if (idx < N1 + N2) {
        int j = idx - N1;
        int c = j / 512, r = j - c * 512;
        int g = r >> 5, k = r & 31;
        w1T_g[j] = (k < 9) ? (_Float16)w1[c * 144 + g * 9 + k] : (_Float16)0.0f;
    } else if (idx < N1 + N2 + N3) {
        int j = idx - N1 - N2;
        int c = j / 96, r = j - c * 96;
        float o;
        if (r < 32) {
            int g  = r & 15;
            int cf = c * 16 + g;
            float inv = g1[cf] * rsqrtf(v1[cf] + EPSV);
            o = (r < 16) ? inv : (b1[cf] - m1[cf]) * inv + beta1[cf];
        } else {
            int f  = (r - 32) & 31;
            int cf = c * 32 + f;
            float inv = g2[cf] * rsqrtf(v2[cf] + EPSV);
            o = (r < 64) ? inv : (b2[cf] - m2[cf]) * inv + beta2[cf];
        }
        sc_g[j] = o;
    }
}

// ---------------------------------------------------------------------------
// Tower kernel: one block per (c, batch-group of 4). 320 threads = 5 waves.
//  once:    coalesced int4 copies of w2T (448), w1T (64), consts (24 f4)
//  per b:   stage x (f16 parity copies xa/xb)
//           conv1 via mfma_16x16x32_f16 (K 9->32 zero-padded) -> y1T
//           conv2 via 7x mfma_32x32x16_f16; BN+ReLU; 8-wide DPP max -> segmax
//           pool = max of 5 segments -> feat (f16)
// LDS 43008 B (3 blocks/CU). VGPR pinned <=64 via __launch_bounds__(320,8)
// (R6: crossing 64 cost 1.5x). af/a1 fragments re-loaded per batch on purpose
// to avoid holding 32 VGPRs live across the batch loop.
// ---------------------------------------------------------------------------
__global__ __launch_bounds__(320, 8) void tower_kernel(
    const float* __restrict__ x,
    const _Float16* __restrict__ w2T_g, const _Float16* __restrict__ w1T_g,
    const float* __restrict__ sc_g,
    _Float16* __restrict__ featH)
{
    __shared__ __align__(16) _Float16 xa_s[432];             // xa[i] = x_s[i]
    __shared__ __align__(16) _Float16 xb_s[432];             // xb[i] = x_s[i+1]
    __shared__ __align__(16) _Float16 w1T_s[16 * 32];        // [g][k]
    __shared__ __align__(16) _Float16 y1T_s[Y1T_ROWS * Y1T_STRIDE];
    __shared__ __align__(16) _Float16 w2T_s[7 * 512];        // [dt][f][g]
    __shared__ _Float16               segmax_s[32 * 50];     // [f][seg] f16
    __shared__ __align__(16) float    cst_s[96];  // s1[16] sh1[16] s2[32] sh2[32]

    const int c   = blockIdx.x;
    const int tid = threadIdx.x;

    // ---- once-per-block staging (coalesced, no div/cvt/scatter) ----
    {
        const int4* w2src = (const int4*)(w2T_g + (size_t)c * 3584);
        for (int i = tid; i < 448; i += 320) ((int4*)w2T_s)[i] = w2src[i];
        const int4* w1src = (const int4*)(w1T_g + c * 512);
        if (tid < 64) ((int4*)w1T_s)[tid] = w1src[tid];
        const float4* csrc = (const float4*)(sc_g + c * 96);
        if (tid >= 64 && tid < 88) ((float4*)cst_s)[tid - 64] = csrc[tid - 64];
        // zero y1T halo rows 0..2 and 403..405 (6 rows x 18 dwords)
        if (tid >= 88 && tid < 196) {
            int i = tid - 88;
            int r = i / 18, cx = i - r * 18;
            int row = (r < 3) ? r : (400 + r);
            ((int*)y1T_s)[row * 18 + cx] = 0;
        }
    }

    for (int nb = 0; nb < 4; ++nb) {
        const int b = blockIdx.y * 4 + nb;

        // ---- stage x as f16 parity copies ----
        const float* xrow = x + ((size_t)b * C_CH + c) * L_IN;
        for (int i = tid; i < 432; i += 320) {
            float v = (i >= 4 && i < 404) ? xrow[i - 4] : 0.0f;
            _Float16 h = (_Float16)v;
            xa_s[i] = h;
            if (i > 0) xb_s[i - 1] = h;
        }
        if (tid == 0) xb_s[431] = (_Float16)0.0f;
        __syncthreads();

        // ---- conv1 via mfma_16x16x32_f16 -> y1T ----
        // A[m=g][k]=w1T; B[k][n]=x_s[t0+n+k-4] (+4 shift folded into x_s).
        // Lane: n = lane&15, k-group q = lane>>4; parity of n selects copy
        // so the lane's 8-f16 window is dword-aligned.
        {
            const int lane = tid & 63;
            const int wv5  = tid >> 6;
            const int nl   = lane & 15;
            const int q    = lane >> 4;
            union { int4 v; f16x8 h; } a1;
            a1.v = *(const int4*)((const int*)w1T_s + nl * 16 + q * 4);
            float s1r[4], sh1r[4];
#pragma unroll
            for (int r = 0; r < 4; ++r) {
                s1r[r]  = cst_s[q * 4 + r];
                sh1r[r] = cst_s[16 + q * 4 + r];
            }
            const int* xsel = (const int*)((nl & 1) ? xb_s : xa_s);
            for (int tile = 0; tile < 5; ++tile) {
                const int t0 = (wv5 * 5 + tile) * 16;
                const int dw = (t0 + nl + q * 8) >> 1;
                union { int4 v; f16x8 h; } bf;
                bf.v.x = xsel[dw];
                bf.v.y = xsel[dw + 1];
                bf.v.z = xsel[dw + 2];
                bf.v.w = xsel[dw + 3];
                f32x4 acc = {0.0f, 0.0f, 0.0f, 0.0f};
                acc = __builtin_amdgcn_mfma_f32_16x16x32_f16(a1.h, bf.h, acc, 0, 0, 0);
                union { _Float16 h[4]; int2 d; } pk;
#pragma unroll
                for (int r = 0; r < 4; ++r) {
                    float v = acc[r] * s1r[r] + sh1r[r];
                    pk.h[r] = (_Float16)(v > 0.0f ? v : 0.0f);
                }
                *(int2*)((int*)y1T_s + (t0 + nl + 3) * 18 + q * 2) = pk.d;
            }
        }
        __syncthreads();

        // ---- conv2 MFMA + BN/ReLU + in-register 8-seg max ----
        {
            const int wv    = tid >> 6;
            const int lane  = tid & 63;
            const int nlane = lane & 31;
            const int half  = lane >> 5;

            union F8q { int4 q; f16x8 h; } af[7];
#pragma unroll
            for (int dt = 0; dt < 7; ++dt)
                af[dt].q = *(const int4*)((const int*)w2T_s + dt * 256 + nlane * 8 + half * 4);

            for (int tile = wv; tile < 13; tile += 5) {
                const int t0  = tile * 32 + nlane;
                const int t0r = t0 < 400 ? t0 : 399;   // rows > 405 don't exist
                f32x16 acc;
#pragma unroll
                for (int i = 0; i < 16; ++i) acc[i] = 0.0f;

#pragma unroll
                for (int dt = 0; dt < 7; ++dt) {
                    const int* p = (const int*)y1T_s + (t0r + dt) * 18 + half * 4;
                    union { int2 d[2]; f16x8 h; } bf;
                    bf.d[0] = *(const int2*)p;
                    bf.d[1] = *(const int2*)(p + 2);
                    acc = __builtin_amdgcn_mfma_f32_32x32x16_f16(af[dt].h, bf.h, acc, 0, 0, 0);
                }

                const bool wr  = ((nlane & 7) == 0) && (t0 < 400);
                const int  seg = t0 >> 3;
#pragma unroll
                for (int reg = 0; reg < 16; ++reg) {
                    int f = (reg & 3) + 8 * (reg >> 2) + 4 * half;
                    float v = acc[reg] * cst_s[32 + f] + cst_s[64 + f];
                    v = fmaxf(v, 0.0f);
                    v = fmaxf(v, dppf<0xB1>(v));    // xor 1
                    v = fmaxf(v, dppf<0x4E>(v));    // xor 2
                    v = fmaxf(v, dppf<0x141>(v));   // row_half_mirror
                    if (wr) segmax_s[f * 50 + seg] = (_Float16)v;
                }
            }
        }
        __syncthreads();

        // ---- pool(40) = max of 5 segment-maxes -> feat f16 ----
        {
            const int f = tid & 31;
            const int p = tid >> 5;
            float m = 0.0f;
#pragma unroll
            for (int k = 0; k < 5; ++k)
                m = fmaxf(m, (float)segmax_s[f * 50 + p * 5 + k]);
            featH[(size_t)b * KFEAT + (c * 32 + f) * 10 + p] = (_Float16)m;
        }
        // no trailing sync needed: next iter's x-stage touches xa/xb only,
        // which nothing reads after this batch's conv1; segmax(i) is fully
        // consumed before any wave can pass the next post-stage sync.
    }
}

// ---------------------------------------------------------------------------
// FC1 f16 MFMA GEMM, split-K without atomics: 173 blocks x KC=320 (20 steps).
// Each block writes a disjoint partial tile part[kb][128][64].
// ---------------------------------------------------------------------------
__global__ __launch_bounds__(256) void fc1_kernel(
    const _Float16* __restrict__ featH, const float* __restrict__ wc1,
    float* __restrict__ part)
{
    const int tid   = threadIdx.x;
    const int kb    = blockIdx.x;
    const int k0    = kb * 320;
    const int lane  = tid & 63;
    const int wv    = tid >> 6;
    const int nlane = lane & 31;
    const int half  = lane >> 5;
    const int jrow  = wv * 32 + nlane;

    const float*    ap  = wc1   + (size_t)jrow * KFEAT + k0 + half * 8;
    const _Float16* b0p = featH + (size_t)nlane * KFEAT + k0 + half * 8;
    const _Float16* b1p = featH + (size_t)(nlane + 32) * KFEAT + k0 + half * 8;

    f32x16 acc0, acc1;
#pragma unroll
    for (int i = 0; i < 16; ++i) { acc0[i] = 0.0f; acc1[i] = 0.0f; }

#pragma unroll 2
    for (int s = 0; s < 20; ++s) {
        const float4 aw0 = *(const float4*)(ap + s * 16);
        const float4 aw1 = *(const float4*)(ap + s * 16 + 4);
        union { fp16x2 v2[4]; f16x8 h; } a;
        a.v2[0] = __builtin_amdgcn_cvt_pkrtz(aw0.x, aw0.y);
        a.v2[1] = __builtin_amdgcn_cvt_pkrtz(aw0.z, aw0.w);
        a.v2[2] = __builtin_amdgcn_cvt_pkrtz(aw1.x, aw1.y);
        a.v2[3] = __builtin_amdgcn_cvt_pkrtz(aw1.z, aw1.w);

        union { int4 q; f16x8 h; } b0, b1;
        b0.q = *(const int4*)(b0p + s * 16);
        b1.q = *(const int4*)(b1p + s * 16);

        acc0 = __builtin_amdgcn_mfma_f32_32x32x16_f16(a.h, b0.h, acc0, 0, 0, 0);
        acc1 = __builtin_amdgcn_mfma_f32_32x32x16_f16(a.h, b1.h, acc1, 0, 0, 0);
    }

    float* pt = part + (size_t)kb * 8192;
#pragma unroll
    for (int reg = 0; reg < 16; ++reg) {
        int j = wv * 32 + (reg & 3) + 8 * (reg >> 2) + 4 * half;
        pt[j * 64 + nlane]      = acc0[reg];
        pt[j * 64 + 32 + nlane] = acc1[reg];
    }
}

// ---------------------------------------------------------------------------
// Reduce partials: h[idx] = sum_kb part[kb][idx]. Coalesced.
// ---------------------------------------------------------------------------
__global__ __launch_bounds__(256) void reduce_kernel(
    const float* __restrict__ part, float* __restrict__ h_ws)
{
    const int idx = blockIdx.x * 256 + threadIdx.x;   // 0..8191
    float s = 0.0f;
    for (int kb = 0; kb < 173; ++kb)
        s += part[(size_t)kb * 8192 + idx];
    h_ws[idx] = s;
}

// ---------------------------------------------------------------------------
// FC2: out[b] = bc2 + sum_j wc2[j] * relu(h[j][b] + bc1[j])
// ---------------------------------------------------------------------------
__global__ __launch_bounds__(64) void fc2_kernel(
    const float* __restrict__ h_ws, const float* __restrict__ bc1,
    const float* __restrict__ wc2, const float* __restrict__ bc2,
    float* __restrict__ out)
{
    const int b = threadIdx.x;
    float acc = bc2[0];
    for (int j = 0; j < 128; ++j) {
        float hv = h_ws[j * 64 + b] + bc1[j];
        hv = hv > 0.0f ? hv : 0.0f;
        acc += wc2[j] * hv;
    }
    out[b] = acc;
}

extern "C" void kernel_launch(void* const* d_in, const int* in_sizes, int n_in,
                              void* d_out, int out_size, void* d_ws, size_t ws_size,
                              hipStream_t stream)
{
    const float* x     = (const float*)d_in[0];
    const float* w1    = (const float*)d_in[1];
    const float* b1    = (const float*)d_in[2];
    const float* g1    = (const float*)d_in[3];
    const float* beta1 = (const float*)d_in[4];
    const float* m1    = (const float*)d_in[5];
    const float* v1    = (const float*)d_in[6];
    const float* w2    = (const float*)d_in[7];
    const float* b2    = (const float*)d_in[8];
    const float* g2    = (const float*)d_in[9];
    const float* beta2 = (const float*)d_in[10];
    const float* m2    = (const float*)d_in[11];
    const float* v2    = (const float*)d_in[12];
    const float* wc1   = (const float*)d_in[13];
    const float* bc1   = (const float*)d_in[14];
    const float* wc2   = (const float*)d_in[15];
    const float* bc2   = (const float*)d_in[16];

    char* ws = (char*)d_ws;
    _Float16* featH = (_Float16*)ws;                          // 7,086,080 B
    float*    part  = (float*)(ws + 7086080);                 // 5,668,864 B
    float*    h_ws  = (float*)(ws + 12754944);                // 32,768 B
    _Float16* w2T_g = (_Float16*)(ws + 12787712);             // 1,240,064 B
    _Float16* w1T_g = (_Float16*)(ws + 14027776);             // 177,152 B
    float*    sc_g  = (float*)(ws + 14204928);                // 66,432 B

    hipLaunchKernelGGL(prep_kernel, dim3(2834), dim3(256), 0, stream,
                       w1, b1, g1, beta1, m1, v1,
                       w2, b2, g2, beta2, m2, v2, w2T_g, w1T_g, sc_g);

    hipLaunchKernelGGL(tower_kernel, dim3(C_CH, 16), dim3(320), 0, stream,
                       x, w2T_g, w1T_g, sc_g, featH);

    hipLaunchKernelGGL(fc1_kernel, dim3(173), dim3(256), 0, stream,
                       featH, wc1, part);

    hipLaunchKernelGGL(reduce_kernel, dim3(32), dim3(256), 0, stream,
                       part, h_ws);

    hipLaunchKernelGGL(fc2_kernel, dim3(1), dim3(64), 0, stream,
                       h_ws, bc1, wc2, bc2, (float*)d_out);
}